// Round 3
// baseline (148.408 us; speedup 1.0000x reference)
//
#include <hip/hip_runtime.h>

#define NBATCH 4
#define DDIM   256
#define NN     4096
#define MM     4096
#define NCHUNK 8          // m-chunks (split-K across workgroups)
#define MCHUNK 512        // m per chunk
#define MTILE  64         // m per LDS tile
#define NT     (MCHUNK / MTILE)
#define LOG2E  1.44269504088896340736f

using half8   = __attribute__((ext_vector_type(8))) _Float16;
using floatx4 = __attribute__((ext_vector_type(4))) float;

// ---------- prep: transpose+cvt emb[b][d][n] -> Xh[b][n][d] fp16 (Q pre-scaled 2*log2e);
// ---------- for tgt also emit yyS[b][m] = -log2e*sum d^2 and Vt[b][m] = {v0,v1,v2,1} ----------
__global__ __launch_bounds__(256) void k_prep(const float* __restrict__ src_emb,
                                              const float* __restrict__ tgt_emb,
                                              const float* __restrict__ tgt,
                                              _Float16* __restrict__ Qh,
                                              _Float16* __restrict__ Kh,
                                              float* __restrict__ yyS,
                                              float4* __restrict__ Vt) {
    __shared__ float tile[64][257];                // [n][d] fp32, +1 pad
    __shared__ float psum[8][64];
    int bz = blockIdx.z, tensor = bz >> 2, b = bz & 3;
    const float* in = tensor ? tgt_emb : src_emb;
    _Float16* out = tensor ? Kh : Qh;
    const float scale = tensor ? 1.0f : 2.0f * LOG2E;
    int n0 = blockIdx.x * 64;
    int t = threadIdx.x;

    // load: 32 n-pairs (float2) x 8 d-parts; fused sum-of-squares
    int c2 = t & 31, part = t >> 5;
    const float* ip = in + (size_t)(b * DDIM + part) * NN + n0 + c2 * 2;
    float s0 = 0.f, s1 = 0.f;
#pragma unroll
    for (int i = 0; i < 32; i++) {
        float2 v = *(const float2*)(ip + (size_t)(i * 8) * NN);  // d = part + i*8
        tile[c2 * 2][part + i * 8]     = v.x;
        tile[c2 * 2 + 1][part + i * 8] = v.y;
        s0 = fmaf(v.x, v.x, s0);
        s1 = fmaf(v.y, v.y, s1);
    }
    if (tensor) { psum[part][c2 * 2] = s0; psum[part][c2 * 2 + 1] = s1; }
    __syncthreads();

    // store: fp16, d-contiguous, 16B/lane
    int dg = t & 31, nn = t >> 5;
#pragma unroll
    for (int p = 0; p < 8; p++) {
        int n = p * 8 + nn;
        const float* row = &tile[n][dg * 8];
        half8 h;
#pragma unroll
        for (int k = 0; k < 8; k++) h[k] = (_Float16)(row[k] * scale);
        *(half8*)(out + (size_t)(b * NN + n0 + n) * DDIM + dg * 8) = h;
    }
    if (tensor && t < 64) {
        float s = 0.f;
#pragma unroll
        for (int j = 0; j < 8; j++) s += psum[j][t];
        int m = n0 + t;
        yyS[b * MM + m] = s * (-LOG2E);
        Vt[(size_t)b * MM + m] = make_float4(tgt[(size_t)b * 3 * MM + m],
                                             tgt[(size_t)b * 3 * MM + MM + m],
                                             tgt[(size_t)b * 3 * MM + 2 * MM + m], 1.0f);
    }
}

// ---------- fused flash: per wave 64n x 512m chunk, D=256; async dbuf staging ----------
__global__ __launch_bounds__(256, 2) void k_flash(const _Float16* __restrict__ Qh,
                                                  const _Float16* __restrict__ Kh,
                                                  const float* __restrict__ yyS,
                                                  const float4* __restrict__ Vt,
                                                  float4* __restrict__ Opart,
                                                  float* __restrict__ Mpart) {
    __shared__ __align__(16) _Float16 Kt[2][MTILE * DDIM];   // 2 x 32 KB, XOR-swizzled

    int i = blockIdx.x;
    int xcd = i & 7, sb = i >> 3;
    int grp = xcd + 8 * (sb >> 4);                 // [0,32): (b,chunk) per XCD for L2 locality
    int b = grp >> 3, chunk = grp & 7, ntile = sb & 15;

    int t = threadIdx.x, wave = t >> 6, lane = t & 63, quad = lane >> 4, l15 = lane & 15;
    int n0 = ntile * 256 + wave * 64;
    int m0 = chunk * MCHUNK;

    // persistent Q fragments: 64n x 256d per wave (128 VGPRs)
    const half8* qp = (const half8*)Qh + (size_t)b * NN * 32;
    half8 qf[4][8];
#pragma unroll
    for (int nb = 0; nb < 4; nb++) {
        int n = n0 + nb * 16 + l15;
#pragma unroll
        for (int ds = 0; ds < 8; ds++) qf[nb][ds] = qp[n * 32 + ds * 4 + quad];
    }

    const _Float16* kp = Kh + (size_t)b * MM * DDIM;
    int ssl = lane & 31, shalf = lane >> 5;
    // async global->LDS staging of one 64x256 K-tile; slot = d-group ^ (row&7)
    auto stage = [&](int mt) {
        const _Float16* gb = kp + (size_t)(m0 + mt * MTILE + wave * 16) * DDIM;
        _Float16* lb = &Kt[mt & 1][wave * 16 * DDIM];
#pragma unroll
        for (int it = 0; it < 8; it++) {
            int rl = it * 2 + shalf;                         // row within wave's 16
            int rloc = wave * 16 + rl;                       // row within tile
            int g = (ssl & 24) | ((ssl ^ rloc) & 7);         // swizzled source d-group
            const _Float16* gp = gb + (size_t)rl * DDIM + g * 8;
            __builtin_amdgcn_global_load_lds(
                (const __attribute__((address_space(1))) uint32_t*)(const void*)gp,
                (__attribute__((address_space(3))) uint32_t*)(void*)(lb + it * 2 * DDIM),
                16, 0, 0);
        }
    };

    const floatx4 z4 = {0.f, 0.f, 0.f, 0.f};
    floatx4 o[4] = {z4, z4, z4, z4};               // per-quad-partial {o0,o1,o2,denom}
    float mr[4];
#pragma unroll
    for (int nb = 0; nb < 4; nb++) mr[nb] = -__builtin_inff();

    const float* yb = yyS + (size_t)b * MM;
    const float4* vb = Vt + (size_t)b * MM;
    int r7 = l15 & 7;

    stage(0);
    for (int mt = 0; mt < NT; mt++) {
        __syncthreads();                           // implicit vmcnt(0): tile-mt DMA landed

        // epilogue yy loads FIRST (so their waitcnt doesn't drain the prefetch DMA)
        int jb = m0 + mt * MTILE + quad * 4;       // this quad's global m base
        floatx4 yv[4];
#pragma unroll
        for (int mb = 0; mb < 4; mb++) yv[mb] = *(const floatx4*)(yb + jb + mb * 16);

        if (mt + 1 < NT) stage(mt + 1);            // async prefetch during compute

        const _Float16* Kb = &Kt[mt & 1][0];
        floatx4 acc[4][4];
#pragma unroll
        for (int nb = 0; nb < 4; nb++)
#pragma unroll
            for (int mb = 0; mb < 4; mb++) acc[nb][mb] = z4;

#pragma unroll
        for (int ds = 0; ds < 8; ds++) {
            int slot = (ds * 4 + quad) ^ r7;       // de-swizzle (conflict-free banks)
            half8 a[4];
#pragma unroll
            for (int mb = 0; mb < 4; mb++)
                a[mb] = *(const half8*)(Kb + (size_t)(mb * 16 + l15) * DDIM + slot * 8);
#pragma unroll
            for (int nb = 0; nb < 4; nb++)
#pragma unroll
                for (int mb = 0; mb < 4; mb++)
                    acc[nb][mb] = __builtin_amdgcn_mfma_f32_16x16x32_f16(a[mb], qf[nb][ds], acc[nb][mb], 0, 0, 0);
        }

        // pass 1: per-quad online max/rescale (NO cross-lane ops)
#pragma unroll
        for (int nb = 0; nb < 4; nb++) {
#pragma unroll
            for (int mb = 0; mb < 4; mb++) acc[nb][mb] = acc[nb][mb] + yv[mb];
            floatx4 mx = __builtin_elementwise_max(
                __builtin_elementwise_max(acc[nb][0], acc[nb][1]),
                __builtin_elementwise_max(acc[nb][2], acc[nb][3]));
            float tm = fmaxf(fmaxf(mx[0], mx[1]), fmaxf(mx[2], mx[3]));
            float mn = fmaxf(mr[nb], tm);
            float al = __builtin_amdgcn_exp2f(mr[nb] - mn);
            mr[nb] = mn;
            o[nb] = o[nb] * al;
            floatx4 mnv = {mn, mn, mn, mn};
#pragma unroll
            for (int mb = 0; mb < 4; mb++) acc[nb][mb] = acc[nb][mb] - mnv;
        }
        // pass 2: exp + PV (V from global, L2-hot, quad-broadcast)
#pragma unroll
        for (int mb = 0; mb < 4; mb++) {
            const float4* vp = vb + jb + mb * 16;
            float4 v0 = vp[0], v1 = vp[1], v2 = vp[2], v3 = vp[3];
#pragma unroll
            for (int nb = 0; nb < 4; nb++) {
                floatx4 pa;
#pragma unroll
                for (int r = 0; r < 4; r++) pa[r] = __builtin_amdgcn_exp2f(acc[nb][mb][r]);
                floatx4 oo = o[nb];
                oo += pa[0] * (floatx4){v0.x, v0.y, v0.z, v0.w};
                oo += pa[1] * (floatx4){v1.x, v1.y, v1.z, v1.w};
                oo += pa[2] * (floatx4){v2.x, v2.y, v2.z, v2.w};
                oo += pa[3] * (floatx4){v3.x, v3.y, v3.z, v3.w};
                o[nb] = oo;
            }
        }
    }

    // merge the 4 per-quad partial softmaxes (once per kernel)
#pragma unroll
    for (int nb = 0; nb < 4; nb++) {
        float mq = mr[nb];
        float ma = fmaxf(mq, __shfl_xor(mq, 16, 64));
        ma = fmaxf(ma, __shfl_xor(ma, 32, 64));
        float w = __builtin_amdgcn_exp2f(mq - ma);
        floatx4 ow = o[nb] * w;
#pragma unroll
        for (int c = 0; c < 4; c++) {
            float v = ow[c];
            v += __shfl_xor(v, 16, 64);
            v += __shfl_xor(v, 32, 64);
            ow[c] = v;
        }
        o[nb] = ow;
        mr[nb] = ma;
    }
    if (quad == 0) {
#pragma unroll
        for (int nb = 0; nb < 4; nb++) {
            int n = n0 + nb * 16 + l15;
            size_t idx = (size_t)(chunk * NBATCH + b) * NN + n;
            Opart[idx] = make_float4(o[nb][0], o[nb][1], o[nb][2], o[nb][3]);
            Mpart[idx] = mr[nb];
        }
    }
}

// ---------- combine the 8 m-chunk partials per (b,n) ----------
__global__ __launch_bounds__(128) void k_combine(const float4* __restrict__ Opart,
                                                 const float* __restrict__ Mpart,
                                                 float* __restrict__ out) {
    int idx = blockIdx.x * 128 + threadIdx.x;      // b*NN + n
    int b = idx >> 12, n = idx & (NN - 1);
    float mstar = -__builtin_inff();
#pragma unroll
    for (int j = 0; j < NCHUNK; j++)
        mstar = fmaxf(mstar, Mpart[(size_t)(j * NBATCH + b) * NN + n]);
    float o0 = 0.f, o1 = 0.f, o2 = 0.f, l = 0.f;
#pragma unroll
    for (int j = 0; j < NCHUNK; j++) {
        size_t id = (size_t)(j * NBATCH + b) * NN + n;
        float w = __builtin_amdgcn_exp2f(Mpart[id] - mstar);
        float4 P = Opart[id];
        o0 = fmaf(w, P.x, o0); o1 = fmaf(w, P.y, o1);
        o2 = fmaf(w, P.z, o2); l  = fmaf(w, P.w, l);
    }
    out[(size_t)(b * 3 + 0) * NN + n] = o0 / l;
    out[(size_t)(b * 3 + 1) * NN + n] = o1 / l;
    out[(size_t)(b * 3 + 2) * NN + n] = o2 / l;
}

extern "C" void kernel_launch(void* const* d_in, const int* in_sizes, int n_in,
                              void* d_out, int out_size, void* d_ws, size_t ws_size,
                              hipStream_t stream) {
    const float* tgt     = (const float*)d_in[1];
    const float* src_emb = (const float*)d_in[2];
    const float* tgt_emb = (const float*)d_in[3];
    float* out = (float*)d_out;

    char* ws = (char*)d_ws;
    // ws: Qh 8.39M | Kh 8.39M | yyS 64K | Vt 256K | Opart 2M | Mpart 512K  (~19.7 MB)
    _Float16* Qh  = (_Float16*)(ws);
    _Float16* Kh  = (_Float16*)(ws + 8388608);
    float*    yyS = (float*)   (ws + 16777216);
    float4*   Vt  = (float4*)  (ws + 16842752);
    float4*   Op  = (float4*)  (ws + 17104896);
    float*    Mp  = (float*)   (ws + 19202048);

    hipLaunchKernelGGL(k_prep,    dim3(64, 1, 8), dim3(256), 0, stream,
                       src_emb, tgt_emb, tgt, Qh, Kh, yyS, Vt);
    hipLaunchKernelGGL(k_flash,   dim3(512),      dim3(256), 0, stream, Qh, Kh, yyS, Vt, Op, Mp);
    hipLaunchKernelGGL(k_combine, dim3(128),      dim3(128), 0, stream, Op, Mp, out);
}